// Round 5
// baseline (182.868 us; speedup 1.0000x reference)
//
#include <hip/hip_runtime.h>
#include <math.h>

#define DD   128
#define DI   170
#define BB   4096
#define NNEG 5
#define SQRT_D 11.3137084989847603904f   // sqrt(128)

#define EMB_PITCH 132      // LDS emb row pitch (16B-aligned rows)
#define XPITCH    172      // ws X row pitch in floats (688B, 16B-aligned)
#define X4        43       // float4s per X row (covers 172)

#define R2ROWS 16          // rows per ffn block
#define NROWT  (BB / R2ROWS)          // 256 row tiles
#define NFFN   (NROWT * 3)            // 768 blocks (3 i-tiles: 64,64,42)

#define R3ROWS 8           // rows per out block
#define NOUT   (BB / R3ROWS)          // 512 blocks
#define TASKS  (R3ROWS * (1 + NNEG))  // 48
#define TPW    (TASKS / 4)            // 12

__device__ __forceinline__ float wave_bcast_sum(float v) {
#pragma unroll
    for (int m = 1; m < 64; m <<= 1) v += __shfl_xor(v, m, 64);
    return v;
}

// Prep: inverse L2 norms. Blocks 0..84: W_hidden/W_gate row norms (4 each).
// Block 85: W_ff_out column norms (coalesced row-walk) + zero the output.
__global__ __launch_bounds__(256) void norms_kernel(
    const float* __restrict__ W_hidden,
    const float* __restrict__ W_gate,
    const float* __restrict__ W_ff_out,
    float* __restrict__ inv_h,
    float* __restrict__ inv_g,
    float* __restrict__ inv_f,
    float* __restrict__ out)
{
    if (blockIdx.x < 85) {
        const int wave = threadIdx.x >> 6;
        const int lane = threadIdx.x & 63;
        const int v = blockIdx.x * 4 + wave;          // 0 .. 339
        const float* W = (v < DI) ? W_hidden : W_gate;
        const int row = (v < DI) ? v : v - DI;
        float2 p = ((const float2*)(W + (long)row * DD))[lane];
        float s = wave_bcast_sum(p.x * p.x + p.y * p.y);
        if (lane == 0) {
            float inv = rsqrtf(s);
            if (v < DI) inv_h[row] = inv; else inv_g[row] = inv;
        }
    } else {
        if (threadIdx.x == 0) out[0] = 0.0f;
        const int c = threadIdx.x;                    // column of W_ff_out (D x DI)
        if (c < DI) {
            float s = 0.0f;
#pragma unroll 4
            for (int d = 0; d < DD; ++d) {
                float a = W_ff_out[(long)d * DI + c]; // coalesced across threads
                s += a * a;
            }
            inv_f[c] = rsqrtf(s);
        }
    }
}

// ffn_kernel: phase 1 (gather+normalize 16 emb rows) + phase 2 (h/g/silu -> X).
// Grid = 256 row-tiles x 3 i-tiles; i-split adds blocks at no extra weight
// traffic. Weight access = R2's proven pattern: thread's own row, walked
// linearly (L1 line reuse across d4). One barrier; every thread active.
__global__ __launch_bounds__(256) void ffn_kernel(
    const int*   __restrict__ input_ids,
    const float* __restrict__ W_in,
    const float* __restrict__ W_hidden,
    const float* __restrict__ W_gate,
    const float* __restrict__ hidden_scale,
    const float* __restrict__ gate_scale,
    const float* __restrict__ inv_h,
    const float* __restrict__ inv_g,
    const float* __restrict__ inv_f,
    float* __restrict__ X)
{
    __shared__ __align__(16) float s_emb[R2ROWS][EMB_PITCH];

    const int tid  = threadIdx.x;
    const int wave = tid >> 6;
    const int lane = tid & 63;
    const int bt = blockIdx.x;
    const int it = bt % 3;
    const int rt = bt / 3;
    const int b0 = rt * R2ROWS;
    const int i0 = it * 64;
    const int wi = (it == 2) ? (DI - 128) : 64;   // 42 on the last tile

    // ---- Phase 1: each wave gathers+normalizes 4 rows (parked loads) ----
    int ids[4];
#pragma unroll
    for (int k = 0; k < 4; ++k) ids[k] = input_ids[b0 + wave * 4 + k];  // uniform
    float2 p[4];
#pragma unroll
    for (int k = 0; k < 4; ++k)
        p[k] = ((const float2*)(W_in + (long)ids[k] * DD))[lane];
#pragma unroll
    for (int k = 0; k < 4; ++k) {
        float s = wave_bcast_sum(p[k].x * p[k].x + p[k].y * p[k].y);
        float inv = rsqrtf(s);
        s_emb[wave * 4 + k][2 * lane]     = p[k].x * inv;
        s_emb[wave * 4 + k][2 * lane + 1] = p[k].y * inv;
    }
    __syncthreads();

    // ---- Phase 2: wave w handles rows 4w..4w+3; lane il -> i = i0+il ----
    const bool act = lane < wi;
    const int i = i0 + (act ? lane : wi - 1);     // clamp; store guarded
    float ah[4] = {0.f, 0.f, 0.f, 0.f};
    float ag[4] = {0.f, 0.f, 0.f, 0.f};
    const float4* wh = (const float4*)(W_hidden + (long)i * DD);
    const float4* wg = (const float4*)(W_gate   + (long)i * DD);
#pragma unroll 4
    for (int d4 = 0; d4 < DD / 4; ++d4) {
        float4 h4 = wh[d4];
        float4 g4 = wg[d4];
#pragma unroll
        for (int j = 0; j < 4; ++j) {
            float4 e4 = *(const float4*)&s_emb[wave * 4 + j][4 * d4];  // broadcast
            ah[j] += e4.x * h4.x + e4.y * h4.y + e4.z * h4.z + e4.w * h4.w;
            ag[j] += e4.x * g4.x + e4.y * g4.y + e4.z * g4.z + e4.w * g4.w;
        }
    }
    const float hs = hidden_scale[i] * inv_h[i];
    const float gs = gate_scale[i]   * inv_g[i] * SQRT_D;
    const float fi = inv_f[i];
    if (act) {
#pragma unroll
        for (int j = 0; j < 4; ++j) {
            const float h = ah[j] * hs;
            const float g = ag[j] * gs;
            const float x = (g / (1.0f + __expf(-g))) * h;   // silu(g) * h
            X[(long)(b0 + wave * 4 + j) * XPITCH + i] = x * fi;  // coalesced
        }
    }
}

// out_kernel: phase 2b (xout = X @ l2n(Wf,0).T, norm already folded into X)
// + phase 3 (gathered logits, negative-sampling loss).
__global__ __launch_bounds__(256) void out_kernel(
    const int*   __restrict__ target_ids,
    const int*   __restrict__ neg_ids,
    const float* __restrict__ W_out,
    const float* __restrict__ W_ff_out,
    const float* __restrict__ logit_scale,
    const float* __restrict__ X,
    float* __restrict__ out)
{
    __shared__ __align__(16) float s_x[R3ROWS][XPITCH];
    __shared__ __align__(16) float s_xout[R3ROWS][DD];
    __shared__ float s_red[4];

    const int tid  = threadIdx.x;
    const int wave = tid >> 6;
    const int lane = tid & 63;
    const int b0   = blockIdx.x * R3ROWS;

    // ---- load X rows (coalesced float4; cols 170..171 junk, never read) ----
#pragma unroll
    for (int idx = tid; idx < R3ROWS * X4; idx += 256) {
        const int r = idx / X4, c = idx - r * X4;
        ((float4*)&s_x[r][0])[c] = ((const float4*)(X + (long)(b0 + r) * XPITCH))[c];
    }
    __syncthreads();

    // ---- Phase 2b (R2's layout): dd = tid&127, r0 = tid>>7, 4 rows each ----
    {
        const int dd = tid & 127;
        const int r0 = tid >> 7;
        float acc[4] = {0.f, 0.f, 0.f, 0.f};
        const float2* wrow = (const float2*)(W_ff_out + (long)dd * DI);
#pragma unroll 5
        for (int i2 = 0; i2 < DI / 2; ++i2) {
            float2 wf = wrow[i2];
#pragma unroll
            for (int k = 0; k < 4; ++k) {
                float2 xv = *(const float2*)&s_x[r0 + 2 * k][2 * i2];
                acc[k] += xv.x * wf.x + xv.y * wf.y;
            }
        }
#pragma unroll
        for (int k = 0; k < 4; ++k) s_xout[r0 + 2 * k][dd] = acc[k];
    }
    __syncthreads();

    // ---- Phase 3: parked W_out loads, then reduce chains ----
    float dotp[TPW], ssp[TPW], lsc[TPW];
    const int tbase = wave * TPW;
#pragma unroll
    for (int k = 0; k < TPW; ++k) {
        const int t  = tbase + k;
        const int r  = t / (1 + NNEG);
        const int jj = t % (1 + NNEG);
        const int bidx = b0 + r;
        const int id = (jj == 0) ? target_ids[bidx] : neg_ids[bidx * NNEG + jj - 1];
        const float* wrow = W_out + (long)id * DD;
        float w0 = wrow[lane], w1 = wrow[64 + lane];
        float x0 = s_xout[r][lane], x1 = s_xout[r][64 + lane];
        dotp[k] = w0 * x0 + w1 * x1;
        ssp[k]  = w0 * w0 + w1 * w1;
        lsc[k]  = logit_scale[id];
    }
    float wacc = 0.0f;
#pragma unroll
    for (int k = 0; k < TPW; ++k) {
        float dot = dotp[k], ss = ssp[k];
#pragma unroll
        for (int m = 1; m < 64; m <<= 1) {
            dot += __shfl_xor(dot, m, 64);
            ss  += __shfl_xor(ss,  m, 64);
        }
        const int jj = (tbase + k) % (1 + NNEG);
        const float logit = dot * rsqrtf(ss) * lsc[k] * SQRT_D;
        const float z  = (jj == 0) ? logit : -logit;
        const float ls = fminf(z, 0.0f) - log1pf(__expf(-fabsf(z)));   // stable log_sigmoid
        wacc += (jj == 0) ? ls * (1.0f / BB) : ls * (1.0f / (BB * NNEG));
    }
    if (lane == 0) s_red[wave] = wacc;
    __syncthreads();
    if (tid == 0) {
        float tot = s_red[0] + s_red[1] + s_red[2] + s_red[3];
        atomicAdd(out, -tot);
    }
}

extern "C" void kernel_launch(void* const* d_in, const int* in_sizes, int n_in,
                              void* d_out, int out_size, void* d_ws, size_t ws_size,
                              hipStream_t stream) {
    (void)in_sizes; (void)n_in; (void)out_size; (void)ws_size;
    const int*   input_ids    = (const int*)  d_in[0];
    const int*   target_ids   = (const int*)  d_in[1];
    const int*   neg_ids      = (const int*)  d_in[2];
    const float* W_in         = (const float*)d_in[3];
    const float* W_out        = (const float*)d_in[4];
    const float* W_hidden     = (const float*)d_in[5];
    const float* W_gate       = (const float*)d_in[6];
    const float* W_ff_out     = (const float*)d_in[7];
    const float* hidden_scale = (const float*)d_in[8];
    const float* gate_scale   = (const float*)d_in[9];
    const float* logit_scale  = (const float*)d_in[10];
    float* out = (float*)d_out;

    // ws layout (floats): X [4096*172] (2.82 MB), then inv arrays
    float* X     = (float*)d_ws;
    float* inv_h = X + (long)BB * XPITCH;
    float* inv_g = inv_h + DI;
    float* inv_f = inv_g + DI;

    norms_kernel<<<86, 256, 0, stream>>>(W_hidden, W_gate, W_ff_out,
                                         inv_h, inv_g, inv_f, out);
    ffn_kernel<<<NFFN, 256, 0, stream>>>(input_ids, W_in, W_hidden, W_gate,
                                         hidden_scale, gate_scale,
                                         inv_h, inv_g, inv_f, X);
    out_kernel<<<NOUT, 256, 0, stream>>>(target_ids, neg_ids, W_out, W_ff_out,
                                         logit_scale, X, out);
}